// Round 2
// baseline (138.189 us; speedup 1.0000x reference)
//
#include <hip/hip_runtime.h>

// out[n,o,j,i] = sum_{a,b} inp[n,2,i+a,j+b] * kt[o,a,b]
//   inp: (32,3,224,224) f32, kt: (64,5,5) f32, out: (32,64,220,220) f32
// i (output row index into the input's H) is the INNERMOST output dim after
// the swapaxes. 220 = 55*4, so each lane owns an aligned quad of 4
// consecutive i values in one output column j -> float4 stores, and each
// block writes 4KB contiguous per output channel.

#define IMG    224
#define OHW    220
#define FLAT   (OHW * OHW)     // 48400
#define NOUT   64
#define KW     5
#define QPC    55              // quads per output column (220/4)
#define NQ     (QPC * OHW)     // 12100 quads per (n)
#define BLOCK  256
#define COLS   10              // input columns staged per block
#define PITCH  11              // padded LDS row pitch
#define SLAB   (IMG * PITCH)   // 2464 floats = 9856 B

__global__ __launch_bounds__(BLOCK, 4)
void ConvolutionalLayer_88742614270062_kernel(const float* __restrict__ inp,
                                              const float* __restrict__ kt,
                                              float* __restrict__ out) {
    __shared__ float s[SLAB];

    const int n   = blockIdx.y;
    const int q0  = blockIdx.x * BLOCK;     // first quad this block owns
    const int jlo = q0 / QPC;               // first output column touched

    // channel 2 of image n
    const float* __restrict__ xb = inp + ((size_t)(n * 3 + 2)) * (IMG * IMG);

    // Stage all 224 input rows x 10 columns (block spans <=6 output columns,
    // +4 for the kernel width). Guard the right edge.
    for (int idx = threadIdx.x; idx < IMG * COLS; idx += BLOCK) {
        int r   = idx / COLS;
        int c   = idx - r * COLS;
        int col = jlo + c;
        s[r * PITCH + c] = (col < IMG) ? xb[r * IMG + col] : 0.0f;
    }
    __syncthreads();

    const int q = q0 + (int)threadIdx.x;
    if (q >= NQ) return;

    const int j  = q / QPC;                 // output column (input W index)
    const int i4 = (q - j * QPC) * 4;       // first of 4 output rows
    const int cj = j - jlo;                 // 0..5

    // 8 rows x 5 cols window covers all four pixels' 5x5 receptive fields.
    float win[KW + 3][KW];
#pragma unroll
    for (int r = 0; r < KW + 3; ++r) {
#pragma unroll
        for (int b = 0; b < KW; ++b) {
            win[r][b] = s[(i4 + r) * PITCH + cj + b];
        }
    }

    float* __restrict__ op = out + (size_t)n * (NOUT * FLAT) + j * OHW + i4;

    // One (wave-uniform) weight load feeds 4 FMAs.
#pragma unroll 2
    for (int o = 0; o < NOUT; ++o) {
        float a0 = 0.f, a1 = 0.f, a2 = 0.f, a3 = 0.f;
#pragma unroll
        for (int a = 0; a < KW; ++a) {
#pragma unroll
            for (int b = 0; b < KW; ++b) {
                float w = kt[o * (KW * KW) + a * KW + b];
                a0 = fmaf(w, win[a    ][b], a0);
                a1 = fmaf(w, win[a + 1][b], a1);
                a2 = fmaf(w, win[a + 2][b], a2);
                a3 = fmaf(w, win[a + 3][b], a3);
            }
        }
        float4 v = make_float4(a0, a1, a2, a3);
        *reinterpret_cast<float4*>(op + (size_t)o * FLAT) = v;  // 16B aligned
    }
}

extern "C" void kernel_launch(void* const* d_in, const int* in_sizes, int n_in,
                              void* d_out, int out_size, void* d_ws, size_t ws_size,
                              hipStream_t stream) {
    const float* inp = (const float*)d_in[0];   // (32,3,224,224)
    const float* kt  = (const float*)d_in[1];   // (64,5,5)
    float* out       = (float*)d_out;           // (32,64,220,220)

    dim3 grid((NQ + BLOCK - 1) / BLOCK, 32);    // 48 x 32 blocks
    ConvolutionalLayer_88742614270062_kernel<<<grid, BLOCK, 0, stream>>>(inp, kt, out);
}